// Round 12
// baseline (656.343 us; speedup 1.0000x reference)
//
#include <hip/hip_runtime.h>
#include <math.h>

// Problem constants (z: [2,16384,256] f32, emb: [8192,256] f32)
#define D_DIM 256
#define NE    8192
#define M_TOT 32768L

// Output layout (f32 elements): z_q_st | loss | idx | age | usage
#define O_LOSS  8388608L
#define O_IDX   8388609L
#define O_AGE   8421377L
#define O_USAGE 8429569L

typedef __attribute__((ext_vector_type(8))) short bf16x8;
typedef __attribute__((ext_vector_type(4))) short bf16x4;
typedef __attribute__((ext_vector_type(4))) float f32x4;
typedef __attribute__((address_space(1))) const void gv_t;
typedef __attribute__((address_space(3))) void lv_t;

__device__ __forceinline__ short f2bf(float f) {   // RNE f32 -> bf16 bits
  unsigned u = __float_as_uint(f);
  u += 0x7FFFu + ((u >> 16) & 1u);
  return (short)(u >> 16);
}
__device__ __forceinline__ float bf2f(short s) {
  return __uint_as_float(((unsigned)(unsigned short)s) << 16);
}

// ---------------------------------------------------------------------------
// Kernel 1: row norms (f64-acc, f32-rounded), age/usage init, loss/cnt init,
// fused emb bf16 hi/lo split (when ws permits).
__global__ __launch_bounds__(256) void vq_prep(
    const float* __restrict__ z, const float* __restrict__ emb,
    const float* __restrict__ code_age, const float* __restrict__ code_usage,
    float* __restrict__ out, float* __restrict__ zzf, float* __restrict__ enf,
    int* __restrict__ cnt, short* __restrict__ emb_h, short* __restrict__ emb_l,
    int do_split) {
  int t = blockIdx.x * 256 + threadIdx.x;  // 0..32767
  {
    const float4* row = reinterpret_cast<const float4*>(z + (size_t)t * D_DIM);
    double s = 0.0;
#pragma unroll
    for (int q = 0; q < D_DIM / 4; ++q) {
      float4 v = row[q];
      s = fma((double)v.x, (double)v.x, s);
      s = fma((double)v.y, (double)v.y, s);
      s = fma((double)v.z, (double)v.z, s);
      s = fma((double)v.w, (double)v.w, s);
    }
    zzf[t] = (float)s;
  }
  if (t < NE) {
    const float4* row = reinterpret_cast<const float4*>(emb + (size_t)t * D_DIM);
    double s = 0.0;
#pragma unroll
    for (int q = 0; q < D_DIM / 4; ++q) {
      float4 v = row[q];
      s = fma((double)v.x, (double)v.x, s);
      s = fma((double)v.y, (double)v.y, s);
      s = fma((double)v.z, (double)v.z, s);
      s = fma((double)v.w, (double)v.w, s);
    }
    enf[t] = (float)s;
    out[O_AGE + t] = code_age[t] + 1.0f;
    out[O_USAGE + t] = code_usage[t];
    if (t == 0) { out[O_LOSS] = 0.0f; *cnt = 0; }
  }
  if (do_split) {
    // 524288 float4 of emb, 16 per thread, coalesced stride
#pragma unroll
    for (int i = 0; i < 16; ++i) {
      int e4 = t + i * 32768;
      float4 v = reinterpret_cast<const float4*>(emb)[e4];
      float s[4] = {v.x, v.y, v.z, v.w};
      short h[4], l[4];
#pragma unroll
      for (int k = 0; k < 4; ++k) {
        h[k] = f2bf(s[k]);
        l[k] = f2bf(s[k] - bf2f(h[k]));
      }
      *reinterpret_cast<bf16x4*>(emb_h + (size_t)e4 * 4) = (bf16x4){h[0], h[1], h[2], h[3]};
      *reinterpret_cast<bf16x4*>(emb_l + (size_t)e4 * 4) = (bf16x4){l[0], l[1], l[2], l[3]};
    }
  }
}

// ---------------------------------------------------------------------------
// Kernel 2: split-bf16 MFMA argmin. GLDS=1: global_load_lds staging from
// pre-split planes via deswizzled per-lane source addrs (linear LDS dest =
// swizzled layout), 4-buffer depth-2 pipeline, counted vmcnt(2), one raw
// barrier per ks. GLDS=0 fallback: classic 2-barrier reg staging with
// in-loop f32->bf16 split (same swizzled layout).
// Layout (shorts): P(r,q8) = (r*32 + q8*8) ^ ((r&7)<<3), r=row, q8=16B group.
#define CHUNK 4096
#define MSPLIT 4
#define SLDS 4096   // shorts per buffer slice (128 rows x 32 shorts)

template <int GLDS>
__global__ __launch_bounds__(512, 2) void vq_argmin_mfma(
    const float* __restrict__ z, const float* __restrict__ emb,
    const short* __restrict__ emb_h, const short* __restrict__ emb_l,
    const float* __restrict__ zzf, const float* __restrict__ enf,
    float* __restrict__ pv1, float* __restrict__ pv2, int* __restrict__ pj1) {
  __shared__ short thb[4][SLDS];
  __shared__ short tlb[4][SLDS];
  __shared__ float enfs[CHUNK];

  const int tid = threadIdx.x;
  const int lane = tid & 63;
  const int wave = tid >> 6;        // 0..7
  const int wr = wave >> 1;         // row group 0..3
  const int wc = wave & 1;          // col group 0..1
  const int lrow = lane & 15;
  const int lq = lane >> 4;         // 0..3
  const size_t row0 = (size_t)blockIdx.x * 128;
  const int jbase = blockIdx.y * CHUNK;

  // phase-1 / fallback staging map (reg->LDS): row srow, 16B group sq
  const int srow = tid >> 2;
  const int sq = tid & 3;
  const int woff = (srow * 32 + sq * 8) ^ ((srow & 7) << 3);   // shorts

  // glds source deswizzle: lane tid's 16B lands at LDS offset tid*16, which
  // is logical (gr, gq) under the swizzle
  const int gr = ((tid >> 3) << 1) | (((tid >> 2) & 1) ^ ((tid >> 4) & 1));
  const int gq = (tid & 3) ^ (gr & 3);
  const int gbase = gr * D_DIM + gq * 8;            // shorts within slice-set
  const int ldst = wave * 512;                       // wave-uniform LDS base

  // fragment read bases (XOR swizzle; r&7 == lrow&7 for all our rows)
  const int sw = (lrow & 7) << 3;
  const int aro = ((wr * 32 + lrow) * 32 + lq * 8) ^ sw;   // + rt*512
  const int cro = ((wc * 64 + lrow) * 32 + lq * 8) ^ sw;   // + ct*512

  // ---- enf -> LDS (read later via ds_read: keeps vmem queue = glds only)
  for (int i = tid; i < CHUNK; i += 512) enfs[i] = enf[jbase + i];

  // ---- phase 1: split A (z rows) into register fragments, full K ----
  bf16x8 afh[2][8], afl[2][8];
#pragma unroll
  for (int ks = 0; ks < 8; ++ks) {
    __syncthreads();
    {
      const float* src = z + (row0 + srow) * (size_t)D_DIM + ks * 32 + sq * 8;
      float4 v0 = *reinterpret_cast<const float4*>(src);
      float4 v1 = *reinterpret_cast<const float4*>(src + 4);
      float s[8] = {v0.x, v0.y, v0.z, v0.w, v1.x, v1.y, v1.z, v1.w};
      short h[8], l[8];
#pragma unroll
      for (int i = 0; i < 8; ++i) {
        h[i] = f2bf(s[i]);
        l[i] = f2bf(s[i] - bf2f(h[i]));
      }
      *reinterpret_cast<bf16x8*>(&thb[0][woff]) = (bf16x8){h[0], h[1], h[2], h[3], h[4], h[5], h[6], h[7]};
      *reinterpret_cast<bf16x8*>(&tlb[0][woff]) = (bf16x8){l[0], l[1], l[2], l[3], l[4], l[5], l[6], l[7]};
    }
    __syncthreads();
#pragma unroll
    for (int rt = 0; rt < 2; ++rt) {
      afh[rt][ks] = *reinterpret_cast<const bf16x8*>(&thb[0][aro + rt * 512]);
      afl[rt][ks] = *reinterpret_cast<const bf16x8*>(&tlb[0][aro + rt * 512]);
    }
  }

  float zrow2[8];
#pragma unroll
  for (int rt = 0; rt < 2; ++rt)
#pragma unroll
    for (int rr = 0; rr < 4; ++rr)
      zrow2[rt * 4 + rr] = zzf[row0 + wr * 32 + rt * 16 + lq * 4 + rr];

  float bv1[8], bv2[8];
  int bj1[8];
#pragma unroll
  for (int s = 0; s < 8; ++s) { bv1[s] = INFINITY; bv2[s] = INFINITY; bj1[s] = 0; }

  // glds source pointers (per-lane) + running slice offset (wave-uniform)
  const short* gph = emb_h + (size_t)jbase * D_DIM + gbase;
  const short* gpl = emb_l + (size_t)jbase * D_DIM + gbase;
  int soff = 0;   // short offset of the slice being issued

  if (GLDS) {
    __syncthreads();   // phase-1 reads of thb[0]/tlb[0] complete everywhere
    // prologue: issue slice 0 -> buf0, slice 1 -> buf1
    __builtin_amdgcn_global_load_lds((gv_t*)(gph + 0), (lv_t*)&thb[0][ldst], 16, 0, 0);
    __builtin_amdgcn_global_load_lds((gv_t*)(gpl + 0), (lv_t*)&tlb[0][ldst], 16, 0, 0);
    __builtin_amdgcn_global_load_lds((gv_t*)(gph + 32), (lv_t*)&thb[1][ldst], 16, 0, 0);
    __builtin_amdgcn_global_load_lds((gv_t*)(gpl + 32), (lv_t*)&tlb[1][ldst], 16, 0, 0);
    soff = 64;   // slice 2
    asm volatile("s_waitcnt vmcnt(2)" ::: "memory");   // slice 0 landed
    __builtin_amdgcn_s_barrier();
    asm volatile("" ::: "memory");
  }

  // ---- main loop; invariant at ks: buf[ks&3] holds slice s (landed),
  // buf[(ks+1)&3] holds s+1 (landed by this ks's vmcnt+barrier),
  // glds for s+2 issued into buf[(ks+2)&3].
  for (int jt0 = jbase; jt0 < jbase + CHUNK; jt0 += 128) {
    f32x4 acc[2][4];
#pragma unroll
    for (int rt = 0; rt < 2; ++rt)
#pragma unroll
      for (int ct = 0; ct < 4; ++ct) acc[rt][ct] = (f32x4){0.f, 0.f, 0.f, 0.f};

#pragma unroll
    for (int ks = 0; ks < 8; ++ks) {
      const int p = GLDS ? (ks & 3) : 0;
      if (!GLDS) {
        __syncthreads();
        const float* src = emb + (size_t)(jt0 + srow) * D_DIM + ks * 32 + sq * 8;
        float4 v0 = *reinterpret_cast<const float4*>(src);
        float4 v1 = *reinterpret_cast<const float4*>(src + 4);
        float s[8] = {v0.x, v0.y, v0.z, v0.w, v1.x, v1.y, v1.z, v1.w};
        short h[8], l[8];
#pragma unroll
        for (int i = 0; i < 8; ++i) {
          h[i] = f2bf(s[i]);
          l[i] = f2bf(s[i] - bf2f(h[i]));
        }
        *reinterpret_cast<bf16x8*>(&thb[0][woff]) = (bf16x8){h[0], h[1], h[2], h[3], h[4], h[5], h[6], h[7]};
        *reinterpret_cast<bf16x8*>(&tlb[0][woff]) = (bf16x8){l[0], l[1], l[2], l[3], l[4], l[5], l[6], l[7]};
        __syncthreads();
      }

      bf16x8 bfh[4];
#pragma unroll
      for (int ct = 0; ct < 4; ++ct)
        bfh[ct] = *reinterpret_cast<const bf16x8*>(&thb[p][cro + ct * 512]);

      if (GLDS) {   // issue prefetch of slice s+2 (stays in flight)
        __builtin_amdgcn_global_load_lds((gv_t*)(gph + soff),
                                         (lv_t*)&thb[(ks + 2) & 3][ldst], 16, 0, 0);
        __builtin_amdgcn_global_load_lds((gv_t*)(gpl + soff),
                                         (lv_t*)&tlb[(ks + 2) & 3][ldst], 16, 0, 0);
        soff += (((ks + 2) & 7) == 7) ? (128 * D_DIM - 7 * 32) : 32;
      }

      __builtin_amdgcn_s_setprio(1);
#pragma unroll
      for (int rt = 0; rt < 2; ++rt)
#pragma unroll
        for (int ct = 0; ct < 4; ++ct) {
          acc[rt][ct] = __builtin_amdgcn_mfma_f32_16x16x32_bf16(
              afl[rt][ks], bfh[ct], acc[rt][ct], 0, 0, 0);   // zl*eh
          acc[rt][ct] = __builtin_amdgcn_mfma_f32_16x16x32_bf16(
              afh[rt][ks], bfh[ct], acc[rt][ct], 0, 0, 0);   // zh*eh
        }
      __builtin_amdgcn_s_setprio(0);

      bf16x8 bfl[4];
#pragma unroll
      for (int ct = 0; ct < 4; ++ct)
        bfl[ct] = *reinterpret_cast<const bf16x8*>(&tlb[p][cro + ct * 512]);
      __builtin_amdgcn_s_setprio(1);
#pragma unroll
      for (int rt = 0; rt < 2; ++rt)
#pragma unroll
        for (int ct = 0; ct < 4; ++ct)
          acc[rt][ct] = __builtin_amdgcn_mfma_f32_16x16x32_bf16(
              afh[rt][ks], bfl[ct], acc[rt][ct], 0, 0, 0);   // zh*el
      __builtin_amdgcn_s_setprio(0);

      if (GLDS) {
        asm volatile("s_waitcnt lgkmcnt(0)" ::: "memory");   // own LDS reads done
        asm volatile("s_waitcnt vmcnt(2)" ::: "memory");     // slice s+1 landed
        __builtin_amdgcn_s_barrier();
        asm volatile("" ::: "memory");
      }
    }

    // epilogue: reference f32 chain; ascending order + strict < -> lowest idx
#pragma unroll
    for (int ct = 0; ct < 4; ++ct) {
      int gj = jt0 + wc * 64 + ct * 16 + lrow;
      float ef = enfs[(jt0 - jbase) + wc * 64 + ct * 16 + lrow];
#pragma unroll
      for (int rt = 0; rt < 2; ++rt)
#pragma unroll
        for (int rr = 0; rr < 4; ++rr) {
          int s = rt * 4 + rr;
          float t = zrow2[s] - 2.0f * acc[rt][ct][rr];
          float dv = t + ef;
          bj1[s] = (dv < bv1[s]) ? gj : bj1[s];
          bv2[s] = fminf(bv2[s], fmaxf(dv, bv1[s]));
          bv1[s] = fminf(bv1[s], dv);
        }
    }
  }

  // reduce top-2 across the 16 code-lanes (lrow) of each lane quarter
#pragma unroll
  for (int m = 1; m < 16; m <<= 1) {
#pragma unroll
    for (int s = 0; s < 8; ++s) {
      float ov1 = __shfl_xor(bv1[s], m, 16);
      float ov2 = __shfl_xor(bv2[s], m, 16);
      int oj1 = __shfl_xor(bj1[s], m, 16);
      if (ov1 < bv1[s] || (ov1 == bv1[s] && oj1 < bj1[s])) {
        bv2[s] = fminf(bv1[s], ov2);
        bv1[s] = ov1; bj1[s] = oj1;
      } else {
        bv2[s] = fminf(bv2[s], ov1);
      }
    }
  }
  if (lrow == 0) {
#pragma unroll
    for (int s = 0; s < 8; ++s) {
      size_t grow = row0 + wr * 32 + (s >> 2) * 16 + lq * 4 + (s & 3);
      size_t o = (size_t)(blockIdx.y * 2 + wc) * M_TOT + grow;
      pv1[o] = bv1[s]; pv2[o] = bv2[s]; pj1[o] = bj1[s];
    }
  }
}

// ---------------------------------------------------------------------------
// Kernel 3: fold MSPLIT partial top-2s per row; flag ambiguous rows.
__global__ __launch_bounds__(256) void vq_merge(
    const float* __restrict__ pv1, const float* __restrict__ pv2,
    const int* __restrict__ pj1, int* __restrict__ idx_ws,
    int* __restrict__ cnt, int* __restrict__ flagged,
    float* __restrict__ flagv1, int* __restrict__ gnc) {
  int m = blockIdx.x * 256 + threadIdx.x;
  if (m >= M_TOT) return;
  float v1 = INFINITY, v2 = INFINITY;
  int j1 = 0;
#pragma unroll
  for (int s = 0; s < MSPLIT; ++s) {
    float a1 = pv1[(size_t)s * M_TOT + m];
    float a2 = pv2[(size_t)s * M_TOT + m];
    int aj = pj1[(size_t)s * M_TOT + m];
    if (a1 < v1 || (a1 == v1 && aj < j1)) {
      v2 = fminf(v1, a2); v1 = a1; j1 = aj;
    } else {
      v2 = fminf(v2, a1);
    }
  }
  idx_ws[m] = j1;
  float u = ldexpf(1.0f, ilogbf(v2) - 23);
  if (v2 - v1 <= 2.0f * u + 1e-5f) {
    int p = atomicAdd(cnt, 1);
    flagged[p] = m;
    flagv1[p] = v1;
    gnc[p] = 0;
  }
}

// ---------------------------------------------------------------------------
// Kernel 4a: refine candidate scan (unchanged from round 11).
#define LDK 40
#define LSLICE (128 * LDK)
#define RSPLIT 8
#define RCHUNK (NE / RSPLIT)
#define GCAP 16

template <int PRESPLIT>
__global__ __launch_bounds__(512, 2) void vq_refine_scan(
    const float* __restrict__ z, const float* __restrict__ emb,
    const short* __restrict__ emb_h, const short* __restrict__ emb_l,
    const float* __restrict__ zzf, const float* __restrict__ enf,
    const int* __restrict__ cnt, const int* __restrict__ flagged,
    const float* __restrict__ flagv1, int* __restrict__ gnc,
    int* __restrict__ gcj) {
  int n = *cnt;
  if (n > (int)M_TOT) n = (int)M_TOT;
  const int base = blockIdx.x * 128;
  if (base >= n) return;

  __shared__ short th[2][LSLICE];
  __shared__ short tl[2][LSLICE];
  __shared__ int rowm_s[128];
  __shared__ float thr_s[128];
  __shared__ float rzz_s[128];

  const int tid = threadIdx.x;
  const int lane = tid & 63;
  const int wave = tid >> 6;
  const int wr = wave >> 1;
  const int wc = wave & 1;
  const int lrow = lane & 15;
  const int lq = lane >> 4;
  const int cb = blockIdx.y * RCHUNK;

  const int srow = tid >> 2;
  const int skq = (tid & 3) * 8;

  if (tid < 128) {
    bool valid = (base + tid) < n;
    int m = valid ? flagged[base + tid] : flagged[base];
    rowm_s[tid] = m;
    rzz_s[tid] = zzf[m];
    if (valid) {
      float v1 = flagv1[base + tid];
      float u = ldexpf(1.0f, ilogbf(v1) - 23);
      thr_s[tid] = v1 + 4.0f * u + 2.5e-5f;
    } else {
      thr_s[tid] = -INFINITY;
    }
  }

  bf16x8 afh[2][8], afl[2][8];
#pragma unroll
  for (int ks = 0; ks < 8; ++ks) {
    __syncthreads();
    {
      const float* src = z + (size_t)rowm_s[srow] * D_DIM + ks * 32 + skq;
      float4 v0 = *reinterpret_cast<const float4*>(src);
      float4 v1 = *reinterpret_cast<const float4*>(src + 4);
      float s[8] = {v0.x, v0.y, v0.z, v0.w, v1.x, v1.y, v1.z, v1.w};
      short h[8], l[8];
#pragma unroll
      for (int i = 0; i < 8; ++i) {
        h[i] = f2bf(s[i]);
        l[i] = f2bf(s[i] - bf2f(h[i]));
      }
      *reinterpret_cast<bf16x4*>(&th[0][srow * LDK + skq]) = (bf16x4){h[0], h[1], h[2], h[3]};
      *reinterpret_cast<bf16x4*>(&th[0][srow * LDK + skq + 4]) = (bf16x4){h[4], h[5], h[6], h[7]};
      *reinterpret_cast<bf16x4*>(&tl[0][srow * LDK + skq]) = (bf16x4){l[0], l[1], l[2], l[3]};
      *reinterpret_cast<bf16x4*>(&tl[0][srow * LDK + skq + 4]) = (bf16x4){l[4], l[5], l[6], l[7]};
    }
    __syncthreads();
#pragma unroll
    for (int rt = 0; rt < 2; ++rt) {
      int r = wr * 32 + rt * 16 + lrow;
      afh[rt][ks] = *reinterpret_cast<const bf16x8*>(&th[0][r * LDK + lq * 8]);
      afl[rt][ks] = *reinterpret_cast<const bf16x8*>(&tl[0][r * LDK + lq * 8]);
    }
  }

  float zrow2[8], thr8[8];
  int rcix8[8];
#pragma unroll
  for (int rt = 0; rt < 2; ++rt)
#pragma unroll
    for (int rr = 0; rr < 4; ++rr) {
      int s = rt * 4 + rr;
      int lrloc = wr * 32 + rt * 16 + lq * 4 + rr;
      zrow2[s] = rzz_s[lrloc];
      thr8[s] = thr_s[lrloc];
      rcix8[s] = base + lrloc;
    }

  bf16x8 ph, pl;
  float4 pf0, pf1;

  if (PRESPLIT) {
    ph = *reinterpret_cast<const bf16x8*>(emb_h + (size_t)(cb + srow) * D_DIM + skq);
    pl = *reinterpret_cast<const bf16x8*>(emb_l + (size_t)(cb + srow) * D_DIM + skq);
  } else {
    const float* src = emb + (size_t)(cb + srow) * D_DIM + skq;
    pf0 = *reinterpret_cast<const float4*>(src);
    pf1 = *reinterpret_cast<const float4*>(src + 4);
  }
  __syncthreads();
  if (PRESPLIT) {
    *reinterpret_cast<bf16x8*>(&th[0][srow * LDK + skq]) = ph;
    *reinterpret_cast<bf16x8*>(&tl[0][srow * LDK + skq]) = pl;
    ph = *reinterpret_cast<const bf16x8*>(emb_h + (size_t)(cb + srow) * D_DIM + 32 + skq);
    pl = *reinterpret_cast<const bf16x8*>(emb_l + (size_t)(cb + srow) * D_DIM + 32 + skq);
  } else {
    float s[8] = {pf0.x, pf0.y, pf0.z, pf0.w, pf1.x, pf1.y, pf1.z, pf1.w};
    short h[8], l[8];
#pragma unroll
    for (int i = 0; i < 8; ++i) {
      h[i] = f2bf(s[i]);
      l[i] = f2bf(s[i] - bf2f(h[i]));
    }
    *reinterpret_cast<bf16x4*>(&th[0][srow * LDK + skq]) = (bf16x4){h[0], h[1], h[2], h[3]};
    *reinterpret_cast<bf16x4*>(&th[0][srow * LDK + skq + 4]) = (bf16x4){h[4], h[5], h[6], h[7]};
    *reinterpret_cast<bf16x4*>(&tl[0][srow * LDK + skq]) = (bf16x4){l[0], l[1], l[2], l[3]};
    *reinterpret_cast<bf16x4*>(&tl[0][srow * LDK + skq + 4]) = (bf16x4){l[4], l[5], l[6], l[7]};
    const float* src = emb + (size_t)(cb + srow) * D_DIM + 32 + skq;
    pf0 = *reinterpret_cast<const float4*>(src);
    pf1 = *reinterpret_cast<const float4*>(src + 4);
  }
  asm volatile("s_waitcnt lgkmcnt(0)" ::: "memory");
  __builtin_amdgcn_s_barrier();
  asm volatile("" ::: "memory");

  for (int jt0 = cb; jt0 < cb + RCHUNK; jt0 += 128) {
    float enq[4];
#pragma unroll
    for (int ct = 0; ct < 4; ++ct) enq[ct] = enf[jt0 + wc * 64 + ct * 16 + lrow];

    f32x4 acc[2][4];
#pragma unroll
    for (int rt = 0; rt < 2; ++rt)
#pragma unroll
      for (int ct = 0; ct < 4; ++ct) acc[rt][ct] = (f32x4){0.f, 0.f, 0.f, 0.f};

#pragma unroll
    for (int ks = 0; ks < 8; ++ks) {
      const int p = ks & 1;
      bf16x8 bfh[4];
#pragma unroll
      for (int ct = 0; ct < 4; ++ct) {
        int c = wc * 64 + ct * 16 + lrow;
        bfh[ct] = *reinterpret_cast<const bf16x8*>(&th[p][c * LDK + lq * 8]);
      }
      __builtin_amdgcn_s_setprio(1);
#pragma unroll
      for (int rt = 0; rt < 2; ++rt)
#pragma unroll
        for (int ct = 0; ct < 4; ++ct) {
          acc[rt][ct] = __builtin_amdgcn_mfma_f32_16x16x32_bf16(
              afl[rt][ks], bfh[ct], acc[rt][ct], 0, 0, 0);
          acc[rt][ct] = __builtin_amdgcn_mfma_f32_16x16x32_bf16(
              afh[rt][ks], bfh[ct], acc[rt][ct], 0, 0, 0);
        }
      __builtin_amdgcn_s_setprio(0);

      if (PRESPLIT) {
        *reinterpret_cast<bf16x8*>(&th[p ^ 1][srow * LDK + skq]) = ph;
        *reinterpret_cast<bf16x8*>(&tl[p ^ 1][srow * LDK + skq]) = pl;
      } else {
        float s[8] = {pf0.x, pf0.y, pf0.z, pf0.w, pf1.x, pf1.y, pf1.z, pf1.w};
        short h[8], l[8];
#pragma unroll
        for (int i = 0; i < 8; ++i) {
          h[i] = f2bf(s[i]);
          l[i] = f2bf(s[i] - bf2f(h[i]));
        }
        *reinterpret_cast<bf16x4*>(&th[p ^ 1][srow * LDK + skq]) = (bf16x4){h[0], h[1], h[2], h[3]};
        *reinterpret_cast<bf16x4*>(&th[p ^ 1][srow * LDK + skq + 4]) = (bf16x4){h[4], h[5], h[6], h[7]};
        *reinterpret_cast<bf16x4*>(&tl[p ^ 1][srow * LDK + skq]) = (bf16x4){l[0], l[1], l[2], l[3]};
        *reinterpret_cast<bf16x4*>(&tl[p ^ 1][srow * LDK + skq + 4]) = (bf16x4){l[4], l[5], l[6], l[7]};
      }
      {
        int sl = ((jt0 - cb) >> 4) + ks + 2;
        if (sl > RCHUNK / 16 - 1) sl = RCHUNK / 16 - 1;
        const size_t off = ((size_t)(cb + (sl >> 3) * 128 + srow)) * D_DIM
                         + (sl & 7) * 32 + skq;
        if (PRESPLIT) {
          ph = *reinterpret_cast<const bf16x8*>(emb_h + off);
          pl = *reinterpret_cast<const bf16x8*>(emb_l + off);
        } else {
          pf0 = *reinterpret_cast<const float4*>(emb + off);
          pf1 = *reinterpret_cast<const float4*>(emb + off + 4);
        }
      }

      bf16x8 bfl[4];
#pragma unroll
      for (int ct = 0; ct < 4; ++ct) {
        int c = wc * 64 + ct * 16 + lrow;
        bfl[ct] = *reinterpret_cast<const bf16x8*>(&tl[p][c * LDK + lq * 8]);
      }
      __builtin_amdgcn_s_setprio(1);
#pragma unroll
      for (int rt = 0; rt < 2; ++rt)
#pragma unroll
        for (int ct = 0; ct < 4; ++ct)
          acc[rt][ct] = __builtin_amdgcn_mfma_f32_16x16x32_bf16(
              afh[rt][ks], bfl[ct], acc[rt][ct], 0, 0, 0);
      __builtin_amdgcn_s_setprio(0);

      asm volatile("s_waitcnt lgkmcnt(0)" ::: "memory");
      __builtin_amdgcn_s_barrier();
      asm volatile("" ::: "memory");
    }

#pragma unroll
    for (int ct = 0; ct < 4; ++ct) {
      int gj = jt0 + wc * 64 + ct * 16 + lrow;
      float ef = enq[ct];
#pragma unroll
      for (int rt = 0; rt < 2; ++rt)
#pragma unroll
        for (int rr = 0; rr < 4; ++rr) {
          int s = rt * 4 + rr;
          float t = zrow2[s] - 2.0f * acc[rt][ct][rr];
          float dv = t + ef;
          if (dv <= thr8[s]) {
            int p = atomicAdd(&gnc[rcix8[s]], 1);
            if (p < GCAP) gcj[rcix8[s] * GCAP + p] = gj;
          }
        }
    }
  }
}

// ---------------------------------------------------------------------------
// Kernel 4b: refine finish (unchanged from round 11).
__global__ __launch_bounds__(256) void vq_refine_fin(
    const float* __restrict__ z, const float* __restrict__ emb,
    const float* __restrict__ zzf, const float* __restrict__ enf,
    int* __restrict__ idx_ws, const int* __restrict__ cnt,
    const int* __restrict__ flagged, const int* __restrict__ gnc,
    const int* __restrict__ gcj) {
  __shared__ float zs[D_DIM];
  __shared__ float cdv[GCAP];
  __shared__ float rv[256];
  __shared__ int rj[256];

  const int tid = threadIdx.x;
  int n = *cnt;
  if (n > (int)M_TOT) n = (int)M_TOT;

  for (int rc = blockIdx.x; rc < n; rc += gridDim.x) {
    int m = flagged[rc];
    __syncthreads();
    zs[tid] = z[(size_t)m * D_DIM + tid];
    __syncthreads();
    int nc = gnc[rc];
    float rzz = zzf[m];

    if (nc >= 1 && nc <= GCAP) {
      if (tid < nc) {
        int j = gcj[rc * GCAP + tid];
        const float4* er = reinterpret_cast<const float4*>(emb + (size_t)j * D_DIM);
        double a = 0.0;
#pragma unroll 4
        for (int k4 = 0; k4 < D_DIM / 4; ++k4) {
          float4 ev = er[k4];
          float4 zv = *reinterpret_cast<const float4*>(&zs[k4 * 4]);
          a = fma((double)zv.x, (double)ev.x, a);
          a = fma((double)zv.y, (double)ev.y, a);
          a = fma((double)zv.z, (double)ev.z, a);
          a = fma((double)zv.w, (double)ev.w, a);
        }
        float zef = (float)a;
        float t = rzz - 2.0f * zef;
        cdv[tid] = t + enf[j];
      }
      __syncthreads();
      if (tid == 0) {
        float bvv = INFINITY; int bjj = 0x7FFFFFFF;
        for (int c = 0; c < nc; ++c) {
          float dv = cdv[c]; int j = gcj[rc * GCAP + c];
          if (dv < bvv || (dv == bvv && j < bjj)) { bvv = dv; bjj = j; }
        }
        idx_ws[m] = bjj;
      }
    } else if (nc > GCAP) {
      float bvv = INFINITY; int bjj = 0;
      for (int j = tid; j < NE; j += 256) {
        const float4* er = reinterpret_cast<const float4*>(emb + (size_t)j * D_DIM);
        double a = 0.0;
        for (int k4 = 0; k4 < D_DIM / 4; ++k4) {
          float4 ev = er[k4];
          float4 zv = *reinterpret_cast<const float4*>(&zs[k4 * 4]);
          a = fma((double)zv.x, (double)ev.x, a);
          a = fma((double)zv.y, (double)ev.y, a);
          a = fma((double)zv.z, (double)ev.z, a);
          a = fma((double)zv.w, (double)ev.w, a);
        }
        float zef = (float)a;
        float t = rzz - 2.0f * zef;
        float dv = t + enf[j];
        if (dv < bvv) { bvv = dv; bjj = j; }
      }
      rv[tid] = bvv; rj[tid] = bjj;
      __syncthreads();
      for (int s = 128; s > 0; s >>= 1) {
        if (tid < s) {
          float ov = rv[tid + s]; int oj = rj[tid + s];
          if (ov < rv[tid] || (ov == rv[tid] && oj < rj[tid])) {
            rv[tid] = ov; rj[tid] = oj;
          }
        }
        __syncthreads();
      }
      if (tid == 0) idx_ws[m] = rj[0];
    }
    __syncthreads();
  }
}

// ---------------------------------------------------------------------------
// Kernel 5: z_q_st + loss + fused idx/age/usage scatter (dq==0 lane per row).
__global__ __launch_bounds__(256) void vq_gather(
    const float* __restrict__ z, const float* __restrict__ emb,
    const int* __restrict__ idx_ws, float* __restrict__ out) {
  __shared__ float lsum[4];
  size_t e4 = (size_t)blockIdx.x * 256 + threadIdx.x;  // float4 index
  size_t m = e4 >> 6;       // / (D/4)
  int dq = (int)(e4 & 63);
  int j = idx_ws[m];
  if (dq == 0) {
    out[O_IDX + m] = (float)j;
    out[O_AGE + j] = 0.0f;            // benign race: all write 0
    atomicAdd(&out[O_USAGE + j], 1.0f);
  }
  float4 q = *reinterpret_cast<const float4*>(emb + (size_t)j * D_DIM + dq * 4);
  float4 zv = *reinterpret_cast<const float4*>(z + e4 * 4);
  float dx = q.x - zv.x, dy = q.y - zv.y, dz = q.z - zv.z, dw = q.w - zv.w;
  float4 o;
  o.x = zv.x + dx; o.y = zv.y + dy; o.z = zv.z + dz; o.w = zv.w + dw;
  *reinterpret_cast<float4*>(out + e4 * 4) = o;
  float ls = dx * dx + dy * dy + dz * dz + dw * dw;
#pragma unroll
  for (int off = 32; off > 0; off >>= 1) ls += __shfl_down(ls, off, 64);
  if ((threadIdx.x & 63) == 0) lsum[threadIdx.x >> 6] = ls;
  __syncthreads();
  if (threadIdx.x == 0)
    atomicAdd(out + O_LOSS,
              (lsum[0] + lsum[1] + lsum[2] + lsum[3]) * (1.25f / 8388608.f));
}

// ---------------------------------------------------------------------------
// ws layout (f32 slots): zzf[32768] | enf[8192] | idx_ws[32768] | cnt |
//   flagged[32768] | flagv1[32768] | gnc[32768] | gcj[32768*16] |
//   pv1[4*32768] | pv2[4*32768] | pj1[4*32768] |
//   emb_h[2M shorts] | emb_l[2M shorts] | pad 32KB (glds tail over-prefetch)
extern "C" void kernel_launch(void* const* d_in, const int* in_sizes, int n_in,
                              void* d_out, int out_size, void* d_ws, size_t ws_size,
                              hipStream_t stream) {
  const float* z = (const float*)d_in[0];
  const float* emb = (const float*)d_in[1];
  const float* code_age = (const float*)d_in[2];
  const float* code_usage = (const float*)d_in[3];
  float* out = (float*)d_out;

  float* zzf = (float*)d_ws;
  float* enf = zzf + M_TOT;
  int* idx_ws = (int*)(enf + NE);
  int* cnt = idx_ws + M_TOT;
  int* flagged = cnt + 1;
  float* flagv1 = (float*)(flagged + M_TOT);
  int* gnc = (int*)(flagv1 + M_TOT);
  int* gcj = gnc + M_TOT;
  float* pv1 = (float*)(gcj + M_TOT * GCAP);
  float* pv2 = pv1 + MSPLIT * M_TOT;
  int* pj1 = (int*)(pv2 + MSPLIT * M_TOT);
  short* emb_h = (short*)(pj1 + MSPLIT * M_TOT);
  short* emb_l = emb_h + (size_t)NE * D_DIM;

  const size_t ws_need =
      (size_t)((char*)(emb_l + (size_t)NE * D_DIM) - (char*)d_ws) + 32768;
  const bool presplit = ws_size >= ws_need;   // constant -> deterministic

  hipLaunchKernelGGL(vq_prep, dim3(M_TOT / 256), dim3(256), 0, stream,
                     z, emb, code_age, code_usage, out, zzf, enf, cnt,
                     emb_h, emb_l, presplit ? 1 : 0);
  if (presplit) {
    hipLaunchKernelGGL((vq_argmin_mfma<1>), dim3(M_TOT / 128, 2), dim3(512), 0, stream,
                       z, emb, emb_h, emb_l, zzf, enf, pv1, pv2, pj1);
  } else {
    hipLaunchKernelGGL((vq_argmin_mfma<0>), dim3(M_TOT / 128, 2), dim3(512), 0, stream,
                       z, emb, emb_h, emb_l, zzf, enf, pv1, pv2, pj1);
  }
  hipLaunchKernelGGL(vq_merge, dim3(M_TOT / 256), dim3(256), 0, stream,
                     pv1, pv2, pj1, idx_ws, cnt, flagged, flagv1, gnc);
  if (presplit) {
    hipLaunchKernelGGL((vq_refine_scan<1>), dim3(M_TOT / 128, RSPLIT), dim3(512), 0, stream,
                       z, emb, emb_h, emb_l, zzf, enf, cnt, flagged, flagv1, gnc, gcj);
  } else {
    hipLaunchKernelGGL((vq_refine_scan<0>), dim3(M_TOT / 128, RSPLIT), dim3(512), 0, stream,
                       z, emb, emb_h, emb_l, zzf, enf, cnt, flagged, flagv1, gnc, gcj);
  }
  hipLaunchKernelGGL(vq_refine_fin, dim3(256), dim3(256), 0, stream,
                     z, emb, zzf, enf, idx_ws, cnt, flagged, gnc, gcj);
  hipLaunchKernelGGL(vq_gather, dim3((M_TOT * (D_DIM / 4)) / 256), dim3(256), 0, stream,
                     z, emb, idx_ws, out);
}